// Round 11
// baseline (88.597 us; speedup 1.0000x reference)
//
#include <hip/hip_runtime.h>
#include <hip/hip_bf16.h>

#define BB 16
#define NN 128
#define DD 128

typedef __attribute__((ext_vector_type(8))) short s8v;   // 8 bf16 (4 VGPRs)
typedef __attribute__((ext_vector_type(4))) float f4v;   // MFMA C/D

__device__ __forceinline__ unsigned short f2bf(float f) {
    __hip_bfloat16 b = __float2bfloat16(f);
    return *reinterpret_cast<unsigned short*>(&b);
}

// prep: BT[k][rho] (bf16, 128x512): rho 0-127 = WuA^T; 128-255 = G1T;
// 256-383 = G3T; 384-511 = G2T. Plus bmWu[k] (fp32) and hbf (h cast bf16).
__global__ __launch_bounds__(256) void prep_kernel(
    const float* __restrict__ h, const float* __restrict__ Wm,
    const float* __restrict__ bm, const float* __restrict__ Wu,
    unsigned short* __restrict__ BT, float* __restrict__ bmWu,
    unsigned short* __restrict__ hbf) {
    const int g = blockIdx.x, t = threadIdx.x;
    if (g < 48) {
        __shared__ float WuB_s[128][129];           // [kk][k], padded
        for (int p = 0; p < 64; ++p) {
            const int x = p * 256 + t;              // k = x>>7, kk = x&127
            WuB_s[x & 127][x >> 7] = Wu[(x >> 7) * 256 + 128 + (x & 127)];
        }
        __syncthreads();
        const int m = g >> 4, dc = g & 15;
        const int off   = (m == 0) ? 0   : (m == 1) ? 256 : 128;
        const int rbase = (m == 0) ? 128 : (m == 1) ? 256 : 384;
        const int k = t & 127, dh = t >> 7;
        const int d0 = dc * 8 + dh * 4;
        float a0 = 0, a1 = 0, a2 = 0, a3 = 0;
        for (int kk = 0; kk < 128; ++kk) {
            const float wu = WuB_s[kk][k];
            const float* wmp = Wm + kk * 384 + off + d0;
            a0 += wmp[0] * wu; a1 += wmp[1] * wu;
            a2 += wmp[2] * wu; a3 += wmp[3] * wu;
        }
        unsigned short* bp = BT + (size_t)k * 512 + rbase + d0;
        bp[0] = f2bf(a0); bp[1] = f2bf(a1); bp[2] = f2bf(a2); bp[3] = f2bf(a3);
    } else if (g == 48) {
        for (int p = 0; p < 64; ++p) {
            const int x = p * 256 + t, k = x >> 7, d = x & 127;
            BT[(size_t)k * 512 + d] = f2bf(Wu[k * 256 + d]);
        }
        if (t < 128) {
            float s = 0.f;
            for (int kk = 0; kk < 128; ++kk) s += bm[kk] * Wu[t * 256 + 128 + kk];
            bmWu[t] = s;
        }
    } else {                                        // g = 49..56: hbf cast
        const int bi = g - 49;
        const float4* h4 = (const float4*)h;
        uint2* hb2 = (uint2*)hbf;
        for (int p = 0; p < 32; ++p) {
            const int i4 = bi * 8192 + p * 256 + t;
            const float4 v = h4[i4];
            hb2[i4] = make_uint2((unsigned)f2bf(v.x) | ((unsigned)f2bf(v.y) << 16),
                                 (unsigned)f2bf(v.z) | ((unsigned)f2bf(v.w) << 16));
        }
    }
}

// es1: i-major STREAMING partial reduction.
// Block = (b, i-chunk of 8, j-half of 64): bid = b*32 + ic*2 + jh.
// Reads e[b, i, j0..j0+64, :] = 32-KB contiguous spans per i (each 32-lane
// group covers 8 consecutive j-fragments); predicated on adj!=0 (holes in a
// sequential stream). 8 float4 register accumulators per thread.
// 512 blocks = 2/CU. Writes 32-KB coalesced fp32 partial per block.
__global__ __launch_bounds__(256) void es1_kernel(const float* __restrict__ e,
                                                  const float* __restrict__ adj,
                                                  float* __restrict__ partial) {
    const int bid = blockIdx.x;
    const int b = bid >> 5, ic = (bid >> 1) & 15, jh = bid & 1;
    const int i0 = ic * 8, j0 = jh * 64;
    const int t = threadIdx.x;

    __shared__ float adj_s[8][64];
    #pragma unroll
    for (int p = 0; p < 2; ++p) {
        const int x = p * 256 + t;                  // row = x>>6 (i), col = x&63 (j')
        adj_s[x >> 6][x & 63] = adj[(size_t)(b * NN + i0 + (x >> 6)) * NN + j0 + (x & 63)];
    }
    __syncthreads();

    const int d4 = t & 31, jg = t >> 5;             // group jg owns j' = jg*8 .. jg*8+7
    const float4* __restrict__ e4 = (const float4*)e;
    f4v acc[8];
    #pragma unroll
    for (int q = 0; q < 8; ++q) acc[q] = (f4v){0.f, 0.f, 0.f, 0.f};

    #pragma unroll 2
    for (int ii = 0; ii < 8; ++ii) {
        const size_t base = ((size_t)(b * NN + i0 + ii) * NN + j0) * 32 + d4;
        #pragma unroll
        for (int q = 0; q < 8; ++q) {
            const float a = adj_s[ii][jg * 8 + q];
            if (a != 0.0f) {                        // skip 512-B hole
                const float4 v = e4[base + (size_t)(jg * 8 + q) * 32];
                acc[q].x += a * v.x; acc[q].y += a * v.y;
                acc[q].z += a * v.z; acc[q].w += a * v.w;
            }
        }
    }
    float4* __restrict__ p4 = (float4*)partial + (size_t)bid * 2048;
    #pragma unroll
    for (int q = 0; q < 8; ++q)
        p4[(size_t)(jg * 8 + q) * 32 + d4] =
            make_float4(acc[q].x, acc[q].y, acc[q].z, acc[q].w);
}

// es2: esbf[b,j,d] = bf16( sum_{ic} partial[b,ic,jh(j)][jrel,d] ).
__global__ __launch_bounds__(256) void es2_kernel(const float* __restrict__ partial,
                                                  unsigned short* __restrict__ esbf) {
    const int idx = blockIdx.x * 256 + threadIdx.x;   // 0..65535
    const int b = idx >> 12, rem = idx & 4095;
    const int j = rem >> 5, d4 = rem & 31;
    const int jh = j >> 6, jrel = j & 63;
    const float4* __restrict__ p4 = (const float4*)partial;
    const size_t off = (size_t)jrel * 32 + d4;
    float4 s = make_float4(0.f, 0.f, 0.f, 0.f);
    #pragma unroll 4
    for (int ic = 0; ic < 16; ++ic) {
        const float4 v = p4[(size_t)(b * 32 + ic * 2 + jh) * 2048 + off];
        s.x += v.x; s.y += v.y; s.z += v.z; s.w += v.w;
    }
    ((uint2*)esbf)[idx] =
        make_uint2((unsigned)f2bf(s.x) | ((unsigned)f2bf(s.y) << 16),
                   (unsigned)f2bf(s.z) | ((unsigned)f2bf(s.w) << 16));
}

// ah: AH[b,j,k] = sum_i adj[i,j]*h[b,i,k] (fp32) -> bf16; also deg[b,j].
__global__ __launch_bounds__(1024) void ah_kernel(
    const float* __restrict__ h, const float* __restrict__ adj,
    unsigned short* __restrict__ AHbf, float* __restrict__ deg) {
    const int blk = blockIdx.x;
    const int b = blk >> 4, jbase = (blk & 15) * 8;
    const int t = threadIdx.x;
    __shared__ float adj_s[8][NN];
    {
        const int i = t >> 3, j2 = t & 7;
        adj_s[j2][i] = adj[(size_t)(b * NN + i) * NN + jbase + j2];
    }
    __syncthreads();
    if (t < 256) {
        const int jj = t >> 5, l = t & 31;
        float s = adj_s[jj][l] + adj_s[jj][l + 32] + adj_s[jj][l + 64] + adj_s[jj][l + 96];
        #pragma unroll
        for (int off = 16; off; off >>= 1) s += __shfl_xor(s, off);
        if (l == 0) deg[b * NN + jbase + jj] = s;
    }
    const int k = t & 127, jl = t >> 7;
    float a0 = 0.f;
    const float* __restrict__ hp = h + (size_t)b * NN * DD + k;
    #pragma unroll 8
    for (int m = 0; m < 32; ++m) {
        const float4 aA = *(const float4*)&adj_s[jl][4 * m];
        const float h0 = hp[(size_t)(4 * m + 0) * DD];
        const float h1 = hp[(size_t)(4 * m + 1) * DD];
        const float h2 = hp[(size_t)(4 * m + 2) * DD];
        const float h3 = hp[(size_t)(4 * m + 3) * DD];
        a0 += aA.x * h0 + aA.y * h1 + aA.z * h2 + aA.w * h3;
    }
    AHbf[(size_t)(b * NN + jbase + jl) * DD + k] = f2bf(a0);
}

// out: MFMA GEMM. acc1 = [h|AH|es]·[WuAT;G1T;G3T]; acc2 = h·G2T.
// out = acc1 + deg*acc2 + deg*bmWu + bu.
__global__ __launch_bounds__(256) void out_kernel(
    const unsigned short* __restrict__ hbf, const unsigned short* __restrict__ AHbf,
    const unsigned short* __restrict__ esbf, const unsigned short* __restrict__ BT,
    const float* __restrict__ deg, const float* __restrict__ bmWu,
    const float* __restrict__ bu, float* __restrict__ out) {
    const int rt = blockIdx.x >> 2, ct = blockIdx.x & 3;
    const int t = threadIdx.x;
    const int l = t & 63, wid = t >> 6, mw = wid >> 1, nw = wid & 1;
    __shared__ unsigned short A_s[32][72], B_s[32][72], B2_s[32][72];
    f4v acc1 = {0.f, 0.f, 0.f, 0.f};
    f4v acc2 = {0.f, 0.f, 0.f, 0.f};
    const int rA = t >> 3, cb = t & 7;
    const int arow = mw * 16 + (l & 15);
    const int brow = nw * 16 + (l & 15);
    const int lg = l >> 4;
    for (int c = 0; c < 6; ++c) {
        __syncthreads();
        const unsigned short* src = (c < 2) ? hbf : (c < 4) ? AHbf : esbf;
        const int col0 = (c & 1) * 64;
        const int rowg = rt * 32 + rA;
        *(s8v*)&A_s[rA][cb * 8] = *(const s8v*)&src[(size_t)rowg * 128 + col0 + cb * 8];
        *(s8v*)&B_s[rA][cb * 8] =
            *(const s8v*)&BT[(size_t)(ct * 32 + rA) * 512 + c * 64 + cb * 8];
        if (c < 2)
            *(s8v*)&B2_s[rA][cb * 8] =
                *(const s8v*)&BT[(size_t)(ct * 32 + rA) * 512 + 384 + c * 64 + cb * 8];
        __syncthreads();
        #pragma unroll
        for (int kit = 0; kit < 2; ++kit) {
            const s8v a  = *(const s8v*)&A_s[arow][kit * 32 + lg * 8];
            const s8v bb = *(const s8v*)&B_s[brow][kit * 32 + lg * 8];
            acc1 = __builtin_amdgcn_mfma_f32_16x16x32_bf16(a, bb, acc1, 0, 0, 0);
            if (c < 2) {
                const s8v b2 = *(const s8v*)&B2_s[brow][kit * 32 + lg * 8];
                acc2 = __builtin_amdgcn_mfma_f32_16x16x32_bf16(a, b2, acc2, 0, 0, 0);
            }
        }
    }
    const int colk = ct * 32 + nw * 16 + (l & 15);
    const float bmv = bmWu[colk], buv = bu[colk];
    #pragma unroll
    for (int r = 0; r < 4; ++r) {
        const int rowg = rt * 32 + mw * 16 + (l >> 4) * 4 + r;
        const float dg = deg[rowg];
        out[(size_t)rowg * 128 + colk] = acc1[r] + dg * acc2[r] + dg * bmv + buv;
    }
}

extern "C" void kernel_launch(void* const* d_in, const int* in_sizes, int n_in,
                              void* d_out, int out_size, void* d_ws, size_t ws_size,
                              hipStream_t stream) {
    const float* h   = (const float*)d_in[0];
    const float* adj = (const float*)d_in[1];
    const float* e   = (const float*)d_in[2];
    const float* Wm  = (const float*)d_in[3];
    const float* bm  = (const float*)d_in[4];
    const float* Wu  = (const float*)d_in[5];
    const float* bu  = (const float*)d_in[6];
    float* out = (float*)d_out;

    float* ws = (float*)d_ws;
    unsigned short* BT   = (unsigned short*)ws;             // 128x512 bf16
    float*          bmWu = ws + 32768;                      // 128 f32
    float*          deg  = ws + 32896;                      // 2048 f32
    unsigned short* hbf  = (unsigned short*)(ws + 34944);   // 2048x128 bf16
    unsigned short* AHbf = (unsigned short*)(ws + 166016);  // 2048x128 bf16
    unsigned short* esbf = (unsigned short*)(ws + 297088);  // 2048x128 bf16
    float*          partial = ws + 428160;                  // 512 x 8192 f32 = 16 MB

    prep_kernel<<<57, 256, 0, stream>>>(h, Wm, bm, Wu, BT, bmWu, hbf);
    es1_kernel<<<512, 256, 0, stream>>>(e, adj, partial);
    es2_kernel<<<256, 256, 0, stream>>>(partial, esbf);
    ah_kernel<<<BB * (NN / 8), 1024, 0, stream>>>(h, adj, AHbf, deg);
    out_kernel<<<256, 256, 0, stream>>>(hbf, AHbf, esbf, BT, deg, bmWu, bu, out);
}

// Round 14
// 57.526 us; speedup vs baseline: 1.5401x; 1.5401x over previous
//
#include <hip/hip_runtime.h>
#include <hip/hip_bf16.h>

#define BB 16
#define NN 128
#define DD 128

typedef __attribute__((ext_vector_type(8))) short s8v;   // 8 bf16 (4 VGPRs)
typedef __attribute__((ext_vector_type(4))) float f4v;   // MFMA C/D

__device__ __forceinline__ unsigned short f2bf(float f) {
    __hip_bfloat16 b = __float2bfloat16(f);
    return *reinterpret_cast<unsigned short*>(&b);
}

// main: block bj = b*128+j (2048 blocks, 256 thr, 8 blocks/CU).
//  - blocks 0..56 first run prep side-jobs (G-GEMMs into BT, WuA copy, bmWu,
//    h->bf16 cast) — hidden under the es stream of the other 1991 blocks.
//  - all blocks: ballot-compact nonzero i's of adj[b,:,j] into an LDS list,
//    then BRANCH-FREE dense gather over the list for es (and ah, deg).
//  R12/R13 bug fixed here: prep's chunk needs 16 KB but aliased a 4 KB
//  array -> LDS overflow corrupted BT. sm_big is 16 KB and serves both as
//  chunk[32][128] (prep) and red[8][32] float4 (es reduction).
__global__ __launch_bounds__(256, 8) void main_kernel(
    const float* __restrict__ h, const float* __restrict__ adj,
    const float* __restrict__ e, const float* __restrict__ Wm,
    const float* __restrict__ bm, const float* __restrict__ Wu,
    unsigned short* __restrict__ BT, float* __restrict__ bmWu,
    unsigned short* __restrict__ hbf, unsigned short* __restrict__ esbf,
    unsigned short* __restrict__ AHbf, float* __restrict__ deg) {
    const int bj = blockIdx.x, t = threadIdx.x;

    __shared__ float  sm_big[4096];       // 16 KB: prep chunk[32][128] / es red[8][32] f4
    __shared__ float  sm_adj[NN];
    __shared__ int    sm_idx[144];
    __shared__ float  sm_av[144];
    __shared__ float  sm_ahp[2][NN];
    __shared__ int    sm_cnt;
    float4 (*sm_red)[32] = (float4 (*)[32])sm_big;

    // ---------------- prep side-jobs ----------------
    if (bj < 48) {
        // G-GEMM: G_m[k][d] = sum_kk Wm[kk, off+d] * Wu[k, 128+kk]
        float* chunk = sm_big;                    // [32][128] = 16 KB (fits now)
        const int m = bj >> 4, dc = bj & 15;
        const int off   = (m == 0) ? 0   : (m == 1) ? 256 : 128;
        const int rbase = (m == 0) ? 128 : (m == 1) ? 256 : 384;
        const int k = t & 127, dh = t >> 7;
        const int d0 = dc * 8 + dh * 4;
        float a0 = 0, a1 = 0, a2 = 0, a3 = 0;
        for (int c = 0; c < 4; ++c) {
            for (int x = t; x < 32 * 128; x += 256) {
                const int kk = x >> 7, kcol = x & 127;
                chunk[kk * 128 + kcol] = Wu[kcol * 256 + 128 + c * 32 + kk];
            }
            __syncthreads();
            #pragma unroll 8
            for (int kk = 0; kk < 32; ++kk) {
                const float wu = chunk[kk * 128 + k];
                const float* wmp = Wm + (c * 32 + kk) * 384 + off + d0;
                a0 += wmp[0] * wu; a1 += wmp[1] * wu;
                a2 += wmp[2] * wu; a3 += wmp[3] * wu;
            }
            __syncthreads();
        }
        unsigned short* bp = BT + (size_t)k * 512 + rbase + d0;
        bp[0] = f2bf(a0); bp[1] = f2bf(a1); bp[2] = f2bf(a2); bp[3] = f2bf(a3);
    } else if (bj == 48) {
        for (int p = 0; p < 64; ++p) {            // WuA^T copy into BT rows 0-127
            const int x = p * 256 + t, k = x >> 7, d = x & 127;
            BT[(size_t)k * 512 + d] = f2bf(Wu[k * 256 + d]);
        }
        if (t < 128) {
            float s = 0.f;
            for (int kk = 0; kk < 128; ++kk) s += bm[kk] * Wu[t * 256 + 128 + kk];
            bmWu[t] = s;
        }
    } else if (bj < 57) {                         // h -> bf16 cast
        const int bi = bj - 49;
        const float4* h4 = (const float4*)h;
        uint2* hb2 = (uint2*)hbf;
        for (int p = 0; p < 32; ++p) {
            const int i4 = bi * 8192 + p * 256 + t;
            const float4 v = h4[i4];
            hb2[i4] = make_uint2((unsigned)f2bf(v.x) | ((unsigned)f2bf(v.y) << 16),
                                 (unsigned)f2bf(v.z) | ((unsigned)f2bf(v.w) << 16));
        }
    }
    __syncthreads();

    // ---------------- es + ah + deg for (b, j) ----------------
    const int b = bj >> 7, j = bj & 127;
    if (t < NN) sm_adj[t] = adj[(size_t)(b * NN + t) * NN + j];
    __syncthreads();

    if (t < 64) {                                 // wave 0: compaction + deg
        const float a0 = sm_adj[t], a1 = sm_adj[t + 64];
        const unsigned long long m0 = __ballot(a0 != 0.0f);
        const unsigned long long m1 = __ballot(a1 != 0.0f);
        const int c0 = __popcll(m0);
        const unsigned long long below = (t == 0) ? 0ull : ((1ull << t) - 1ull);
        const int p0 = __popcll(m0 & below);
        const int p1 = c0 + __popcll(m1 & below);
        if (a0 != 0.0f) { sm_idx[p0] = t;      sm_av[p0] = a0; }
        if (a1 != 0.0f) { sm_idx[p1] = t + 64; sm_av[p1] = a1; }
        const int cnt = c0 + __popcll(m1);
        const int cntP = (cnt + 15) & ~15;
        for (int x = cnt + t; x < cntP + 8; x += 64) { sm_idx[x] = 0; sm_av[x] = 0.f; }
        if (t == 0) sm_cnt = cntP;
        float s = a0 + a1;                        // deg = sum of adj column
        #pragma unroll
        for (int off = 32; off; off >>= 1) s += __shfl_xor(s, off);
        if (t == 0) deg[bj] = s;
    }
    __syncthreads();
    const int cnt = sm_cnt;

    // es: branch-free dense gather over compacted list (unroll 2)
    {
        const int d4 = t & 31, g = t >> 5;
        const float4* __restrict__ ep =
            (const float4*)e + ((size_t)(b * NN) * NN + j) * 32 + d4;
        f4v acc = {0.f, 0.f, 0.f, 0.f};
        for (int n = g; n < cnt; n += 16) {
            const int   iA = sm_idx[n];     const float aA = sm_av[n];
            const int   iB = sm_idx[n + 8]; const float aB = sm_av[n + 8];
            const float4 vA = ep[(size_t)iA * (NN * 32)];
            const float4 vB = ep[(size_t)iB * (NN * 32)];
            acc.x += aA * vA.x + aB * vB.x;
            acc.y += aA * vA.y + aB * vB.y;
            acc.z += aA * vA.z + aB * vB.z;
            acc.w += aA * vA.w + aB * vB.w;
        }
        sm_red[g][d4] = make_float4(acc.x, acc.y, acc.z, acc.w);
    }

    // ah: same list, h rows L2-resident, coalesced across 128 lanes
    {
        const int k = t & 127, ih = t >> 7;
        float ah = 0.f;
        const float* __restrict__ hp = h + (size_t)b * NN * DD + k;
        for (int n = ih; n < cnt; n += 4) {
            const int   i1 = sm_idx[n];     const float A1 = sm_av[n];
            const int   i2 = sm_idx[n + 2]; const float A2 = sm_av[n + 2];
            ah += A1 * hp[(size_t)i1 * DD] + A2 * hp[(size_t)i2 * DD];
        }
        sm_ahp[ih][k] = ah;
    }
    __syncthreads();

    if (t < 32) {                                 // es reduce + bf16 store
        float4 s = sm_red[0][t];
        #pragma unroll
        for (int r = 1; r < 8; ++r) {
            const float4 v = sm_red[r][t];
            s.x += v.x; s.y += v.y; s.z += v.z; s.w += v.w;
        }
        ((uint2*)esbf)[(size_t)bj * 32 + t] =
            make_uint2((unsigned)f2bf(s.x) | ((unsigned)f2bf(s.y) << 16),
                       (unsigned)f2bf(s.z) | ((unsigned)f2bf(s.w) << 16));
    }
    if (t < 128)
        AHbf[(size_t)bj * DD + t] = f2bf(sm_ahp[0][t] + sm_ahp[1][t]);
}

// out: MFMA GEMM (R10-proven). acc1 = [h|AH|es]·[WuAT;G1T;G3T]; acc2 = h·G2T.
// out = acc1 + deg*acc2 + deg*bmWu + bu.
__global__ __launch_bounds__(256) void out_kernel(
    const unsigned short* __restrict__ hbf, const unsigned short* __restrict__ AHbf,
    const unsigned short* __restrict__ esbf, const unsigned short* __restrict__ BT,
    const float* __restrict__ deg, const float* __restrict__ bmWu,
    const float* __restrict__ bu, float* __restrict__ out) {
    const int rt = blockIdx.x >> 2, ct = blockIdx.x & 3;
    const int t = threadIdx.x;
    const int l = t & 63, wid = t >> 6, mw = wid >> 1, nw = wid & 1;
    __shared__ unsigned short A_s[32][72], B_s[32][72], B2_s[32][72];
    f4v acc1 = {0.f, 0.f, 0.f, 0.f};
    f4v acc2 = {0.f, 0.f, 0.f, 0.f};
    const int rA = t >> 3, cb = t & 7;
    const int arow = mw * 16 + (l & 15);
    const int brow = nw * 16 + (l & 15);
    const int lg = l >> 4;
    for (int c = 0; c < 6; ++c) {
        __syncthreads();
        const unsigned short* src = (c < 2) ? hbf : (c < 4) ? AHbf : esbf;
        const int col0 = (c & 1) * 64;
        const int rowg = rt * 32 + rA;
        *(s8v*)&A_s[rA][cb * 8] = *(const s8v*)&src[(size_t)rowg * 128 + col0 + cb * 8];
        *(s8v*)&B_s[rA][cb * 8] =
            *(const s8v*)&BT[(size_t)(ct * 32 + rA) * 512 + c * 64 + cb * 8];
        if (c < 2)
            *(s8v*)&B2_s[rA][cb * 8] =
                *(const s8v*)&BT[(size_t)(ct * 32 + rA) * 512 + 384 + c * 64 + cb * 8];
        __syncthreads();
        #pragma unroll
        for (int kit = 0; kit < 2; ++kit) {
            const s8v a  = *(const s8v*)&A_s[arow][kit * 32 + lg * 8];
            const s8v bb = *(const s8v*)&B_s[brow][kit * 32 + lg * 8];
            acc1 = __builtin_amdgcn_mfma_f32_16x16x32_bf16(a, bb, acc1, 0, 0, 0);
            if (c < 2) {
                const s8v b2 = *(const s8v*)&B2_s[brow][kit * 32 + lg * 8];
                acc2 = __builtin_amdgcn_mfma_f32_16x16x32_bf16(a, b2, acc2, 0, 0, 0);
            }
        }
    }
    const int colk = ct * 32 + nw * 16 + (l & 15);
    const float bmv = bmWu[colk], buv = bu[colk];
    #pragma unroll
    for (int r = 0; r < 4; ++r) {
        const int rowg = rt * 32 + mw * 16 + (l >> 4) * 4 + r;
        const float dg = deg[rowg];
        out[(size_t)rowg * 128 + colk] = acc1[r] + dg * acc2[r] + dg * bmv + buv;
    }
}

extern "C" void kernel_launch(void* const* d_in, const int* in_sizes, int n_in,
                              void* d_out, int out_size, void* d_ws, size_t ws_size,
                              hipStream_t stream) {
    const float* h   = (const float*)d_in[0];
    const float* adj = (const float*)d_in[1];
    const float* e   = (const float*)d_in[2];
    const float* Wm  = (const float*)d_in[3];
    const float* bm  = (const float*)d_in[4];
    const float* Wu  = (const float*)d_in[5];
    const float* bu  = (const float*)d_in[6];
    float* out = (float*)d_out;

    float* ws = (float*)d_ws;
    unsigned short* BT   = (unsigned short*)ws;             // 128x512 bf16
    float*          bmWu = ws + 32768;                      // 128 f32
    float*          deg  = ws + 32896;                      // 2048 f32
    unsigned short* hbf  = (unsigned short*)(ws + 34944);   // 2048x128 bf16
    unsigned short* AHbf = (unsigned short*)(ws + 166016);  // 2048x128 bf16
    unsigned short* esbf = (unsigned short*)(ws + 297088);  // 2048x128 bf16

    main_kernel<<<BB * NN, 256, 0, stream>>>(h, adj, e, Wm, bm, Wu,
                                             BT, bmWu, hbf, esbf, AHbf, deg);
    out_kernel<<<256, 256, 0, stream>>>(hbf, AHbf, esbf, BT, deg, bmWu, bu, out);
}

// Round 15
// 38.687 us; speedup vs baseline: 2.2901x; 1.4870x over previous
//
#include <hip/hip_runtime.h>
#include <hip/hip_bf16.h>

#define BB 16
#define NN 128
#define DD 128

typedef __attribute__((ext_vector_type(8))) short s8v;   // 8 bf16 (4 VGPRs)
typedef __attribute__((ext_vector_type(4))) float f4v;   // MFMA C/D

__device__ __forceinline__ unsigned short f2bf(float f) {
    __hip_bfloat16 b = __float2bfloat16(f);
    return *reinterpret_cast<unsigned short*>(&b);
}

// main: BLOCK-ROLE fusion (no phase barriers, no min-waves reg cap).
//   bid 0..2047     : es role  — R10-proven predicated j-major gather
//   bid 2048..2303  : ah role  — R5-proven 4-accumulator dot, 8 j's/block
//   bid 2304..2351  : prep G-GEMM (16 KB chunk staging — sized correctly)
//   bid 2352        : WuA copy + bmWu
//   bid 2353..2360  : h -> bf16 cast
// Roles are per-block, so ah/prep blocks fill the latency bubbles of the
// es stream instead of serializing after it (R10 ran these as 3 extra
// kernels = ~11 us of serial tail).
__global__ __launch_bounds__(256) void main_kernel(
    const float* __restrict__ h, const float* __restrict__ adj,
    const float* __restrict__ e, const float* __restrict__ Wm,
    const float* __restrict__ bm, const float* __restrict__ Wu,
    unsigned short* __restrict__ BT, float* __restrict__ bmWu,
    unsigned short* __restrict__ hbf, unsigned short* __restrict__ esbf,
    unsigned short* __restrict__ AHbf, float* __restrict__ deg) {
    const int bid = blockIdx.x, t = threadIdx.x;

    __shared__ float sm_big[4096];      // 16 KB: es red / ah adj_s / prep chunk
    __shared__ float sm_adj[NN];        // es role: adj column

    if (bid < 2048) {
        // -------- es role: es[b,j,d] = sum_i adj[i,j]*e[b,i,j,d] --------
        const int b = bid >> 7, j = bid & 127;
        float4 (*red)[32] = (float4 (*)[32])sm_big;
        if (t < NN) sm_adj[t] = adj[(size_t)(b * NN + t) * NN + j];
        __syncthreads();
        const int d4 = t & 31, ig = t >> 5;          // 8 groups x 16 i's
        const float4* __restrict__ e4 =
            (const float4*)e + ((size_t)(b * NN) * NN + j) * 32 + d4;
        const int i0 = ig * 16;
        float4 acc = make_float4(0.f, 0.f, 0.f, 0.f);
        #pragma unroll
        for (int ii = 0; ii < 16; ++ii) {
            const float a = sm_adj[i0 + ii];
            if (a != 0.0f) {                          // skip zero fragment
                const float4 v = e4[(size_t)(i0 + ii) * (NN * 32)];
                acc.x += a * v.x; acc.y += a * v.y;
                acc.z += a * v.z; acc.w += a * v.w;
            }
        }
        red[ig][d4] = acc;
        __syncthreads();
        if (t < 32) {
            float4 s = red[0][t];
            #pragma unroll
            for (int r = 1; r < 8; ++r) {
                const float4 v = red[r][t];
                s.x += v.x; s.y += v.y; s.z += v.z; s.w += v.w;
            }
            ((uint2*)esbf)[(size_t)bid * 32 + t] =
                make_uint2((unsigned)f2bf(s.x) | ((unsigned)f2bf(s.y) << 16),
                           (unsigned)f2bf(s.z) | ((unsigned)f2bf(s.w) << 16));
        }
    } else if (bid < 2304) {
        // -------- ah role: AH[b,j,k] = sum_i adj[i,j]*h[b,i,k]; deg --------
        const int b2 = bid - 2048;
        const int b = b2 >> 4, jbase = (b2 & 15) * 8;
        float (*adj_s)[NN] = (float (*)[NN])sm_big;   // [8][128] = 4 KB
        for (int x = t; x < 8 * NN; x += 256) {
            const int i = x >> 3, j2 = x & 7;
            adj_s[j2][i] = adj[(size_t)(b * NN + i) * NN + jbase + j2];
        }
        __syncthreads();
        {   // deg for the 8 j's: 8 groups of 32 lanes
            const int jj = t >> 5, l = t & 31;
            float s = adj_s[jj][l] + adj_s[jj][l + 32] + adj_s[jj][l + 64] + adj_s[jj][l + 96];
            #pragma unroll
            for (int off = 16; off; off >>= 1) s += __shfl_xor(s, off);
            if (l == 0) deg[b * NN + jbase + jj] = s;
        }
        const int k = t & 127, jh = t >> 7;           // jh = 0/1; j = jh,jh+2,jh+4,jh+6
        float a0 = 0.f, a1 = 0.f, a2 = 0.f, a3 = 0.f;
        const float* __restrict__ hp = h + (size_t)b * NN * DD + k;
        #pragma unroll 8
        for (int m = 0; m < 32; ++m) {
            const float4 aA = *(const float4*)&adj_s[jh][4 * m];
            const float4 aB = *(const float4*)&adj_s[jh + 2][4 * m];
            const float4 aC = *(const float4*)&adj_s[jh + 4][4 * m];
            const float4 aD = *(const float4*)&adj_s[jh + 6][4 * m];
            const float h0 = hp[(size_t)(4 * m + 0) * DD];
            const float h1 = hp[(size_t)(4 * m + 1) * DD];
            const float h2 = hp[(size_t)(4 * m + 2) * DD];
            const float h3 = hp[(size_t)(4 * m + 3) * DD];
            a0 += aA.x * h0 + aA.y * h1 + aA.z * h2 + aA.w * h3;
            a1 += aB.x * h0 + aB.y * h1 + aB.z * h2 + aB.w * h3;
            a2 += aC.x * h0 + aC.y * h1 + aC.z * h2 + aC.w * h3;
            a3 += aD.x * h0 + aD.y * h1 + aD.z * h2 + aD.w * h3;
        }
        AHbf[(size_t)(b * NN + jbase + jh) * DD + k]     = f2bf(a0);
        AHbf[(size_t)(b * NN + jbase + jh + 2) * DD + k] = f2bf(a1);
        AHbf[(size_t)(b * NN + jbase + jh + 4) * DD + k] = f2bf(a2);
        AHbf[(size_t)(b * NN + jbase + jh + 6) * DD + k] = f2bf(a3);
    } else if (bid < 2352) {
        // -------- prep: G_m[k][d] = sum_kk Wm[kk,off+d]*Wu[k,128+kk] --------
        float* chunk = sm_big;                        // [32][128] = 16 KB
        const int g = bid - 2304;
        const int m = g >> 4, dc = g & 15;
        const int off   = (m == 0) ? 0   : (m == 1) ? 256 : 128;
        const int rbase = (m == 0) ? 128 : (m == 1) ? 256 : 384;
        const int k = t & 127, dh = t >> 7;
        const int d0 = dc * 8 + dh * 4;
        float a0 = 0, a1 = 0, a2 = 0, a3 = 0;
        for (int c = 0; c < 4; ++c) {
            for (int x = t; x < 32 * 128; x += 256) {
                const int kk = x >> 7, kcol = x & 127;
                chunk[kk * 128 + kcol] = Wu[kcol * 256 + 128 + c * 32 + kk];
            }
            __syncthreads();
            #pragma unroll 8
            for (int kk = 0; kk < 32; ++kk) {
                const float wu = chunk[kk * 128 + k];
                const float* wmp = Wm + (c * 32 + kk) * 384 + off + d0;
                a0 += wmp[0] * wu; a1 += wmp[1] * wu;
                a2 += wmp[2] * wu; a3 += wmp[3] * wu;
            }
            __syncthreads();
        }
        unsigned short* bp = BT + (size_t)k * 512 + rbase + d0;
        bp[0] = f2bf(a0); bp[1] = f2bf(a1); bp[2] = f2bf(a2); bp[3] = f2bf(a3);
    } else if (bid == 2352) {
        for (int p = 0; p < 64; ++p) {                // WuA^T copy, BT rows 0-127
            const int x = p * 256 + t, k = x >> 7, d = x & 127;
            BT[(size_t)k * 512 + d] = f2bf(Wu[k * 256 + d]);
        }
        if (t < 128) {
            float s = 0.f;
            for (int kk = 0; kk < 128; ++kk) s += bm[kk] * Wu[t * 256 + 128 + kk];
            bmWu[t] = s;
        }
    } else {
        // -------- h -> bf16 cast --------
        const int bi = bid - 2353;
        const float4* h4 = (const float4*)h;
        uint2* hb2 = (uint2*)hbf;
        for (int p = 0; p < 32; ++p) {
            const int i4 = bi * 8192 + p * 256 + t;
            const float4 v = h4[i4];
            hb2[i4] = make_uint2((unsigned)f2bf(v.x) | ((unsigned)f2bf(v.y) << 16),
                                 (unsigned)f2bf(v.z) | ((unsigned)f2bf(v.w) << 16));
        }
    }
}

// out: MFMA GEMM (R10-proven). acc1 = [h|AH|es]·[WuAT;G1T;G3T]; acc2 = h·G2T.
// out = acc1 + deg*acc2 + deg*bmWu + bu.
__global__ __launch_bounds__(256) void out_kernel(
    const unsigned short* __restrict__ hbf, const unsigned short* __restrict__ AHbf,
    const unsigned short* __restrict__ esbf, const unsigned short* __restrict__ BT,
    const float* __restrict__ deg, const float* __restrict__ bmWu,
    const float* __restrict__ bu, float* __restrict__ out) {
    const int rt = blockIdx.x >> 2, ct = blockIdx.x & 3;
    const int t = threadIdx.x;
    const int l = t & 63, wid = t >> 6, mw = wid >> 1, nw = wid & 1;
    __shared__ unsigned short A_s[32][72], B_s[32][72], B2_s[32][72];
    f4v acc1 = {0.f, 0.f, 0.f, 0.f};
    f4v acc2 = {0.f, 0.f, 0.f, 0.f};
    const int rA = t >> 3, cb = t & 7;
    const int arow = mw * 16 + (l & 15);
    const int brow = nw * 16 + (l & 15);
    const int lg = l >> 4;
    for (int c = 0; c < 6; ++c) {
        __syncthreads();
        const unsigned short* src = (c < 2) ? hbf : (c < 4) ? AHbf : esbf;
        const int col0 = (c & 1) * 64;
        const int rowg = rt * 32 + rA;
        *(s8v*)&A_s[rA][cb * 8] = *(const s8v*)&src[(size_t)rowg * 128 + col0 + cb * 8];
        *(s8v*)&B_s[rA][cb * 8] =
            *(const s8v*)&BT[(size_t)(ct * 32 + rA) * 512 + c * 64 + cb * 8];
        if (c < 2)
            *(s8v*)&B2_s[rA][cb * 8] =
                *(const s8v*)&BT[(size_t)(ct * 32 + rA) * 512 + 384 + c * 64 + cb * 8];
        __syncthreads();
        #pragma unroll
        for (int kit = 0; kit < 2; ++kit) {
            const s8v a  = *(const s8v*)&A_s[arow][kit * 32 + lg * 8];
            const s8v bb = *(const s8v*)&B_s[brow][kit * 32 + lg * 8];
            acc1 = __builtin_amdgcn_mfma_f32_16x16x32_bf16(a, bb, acc1, 0, 0, 0);
            if (c < 2) {
                const s8v b2 = *(const s8v*)&B2_s[brow][kit * 32 + lg * 8];
                acc2 = __builtin_amdgcn_mfma_f32_16x16x32_bf16(a, b2, acc2, 0, 0, 0);
            }
        }
    }
    const int colk = ct * 32 + nw * 16 + (l & 15);
    const float bmv = bmWu[colk], buv = bu[colk];
    #pragma unroll
    for (int r = 0; r < 4; ++r) {
        const int rowg = rt * 32 + mw * 16 + (l >> 4) * 4 + r;
        const float dg = deg[rowg];
        out[(size_t)rowg * 128 + colk] = acc1[r] + dg * acc2[r] + dg * bmv + buv;
    }
}

extern "C" void kernel_launch(void* const* d_in, const int* in_sizes, int n_in,
                              void* d_out, int out_size, void* d_ws, size_t ws_size,
                              hipStream_t stream) {
    const float* h   = (const float*)d_in[0];
    const float* adj = (const float*)d_in[1];
    const float* e   = (const float*)d_in[2];
    const float* Wm  = (const float*)d_in[3];
    const float* bm  = (const float*)d_in[4];
    const float* Wu  = (const float*)d_in[5];
    const float* bu  = (const float*)d_in[6];
    float* out = (float*)d_out;

    float* ws = (float*)d_ws;
    unsigned short* BT   = (unsigned short*)ws;             // 128x512 bf16
    float*          bmWu = ws + 32768;                      // 128 f32
    float*          deg  = ws + 32896;                      // 2048 f32
    unsigned short* hbf  = (unsigned short*)(ws + 34944);   // 2048x128 bf16
    unsigned short* AHbf = (unsigned short*)(ws + 166016);  // 2048x128 bf16
    unsigned short* esbf = (unsigned short*)(ws + 297088);  // 2048x128 bf16

    main_kernel<<<2361, 256, 0, stream>>>(h, adj, e, Wm, bm, Wu,
                                          BT, bmWu, hbf, esbf, AHbf, deg);
    out_kernel<<<256, 256, 0, stream>>>(hbf, AHbf, esbf, BT, deg, bmWu, bu, out);
}

// Round 16
// 37.425 us; speedup vs baseline: 2.3673x; 1.0337x over previous
//
#include <hip/hip_runtime.h>
#include <hip/hip_bf16.h>

#define BB 16
#define NN 128
#define DD 128

typedef __attribute__((ext_vector_type(8))) short s8v;   // 8 bf16 (4 VGPRs)
typedef __attribute__((ext_vector_type(4))) float f4v;   // MFMA C/D

__device__ __forceinline__ unsigned short f2bf(float f) {
    __hip_bfloat16 b = __float2bfloat16(f);
    return *reinterpret_cast<unsigned short*>(&b);
}

// prep: BT[k][rho] (bf16, 128x512): rho 0-127 = WuA^T; 128-255 = G1T;
// 256-383 = G3T; 384-511 = G2T. Plus bmWu[k] (fp32) and hbf (h cast bf16).
__global__ __launch_bounds__(256) void prep_kernel(
    const float* __restrict__ h, const float* __restrict__ Wm,
    const float* __restrict__ bm, const float* __restrict__ Wu,
    unsigned short* __restrict__ BT, float* __restrict__ bmWu,
    unsigned short* __restrict__ hbf) {
    const int g = blockIdx.x, t = threadIdx.x;
    if (g < 48) {
        __shared__ float WuB_s[128][129];           // [kk][k], padded
        for (int p = 0; p < 64; ++p) {
            const int x = p * 256 + t;              // k = x>>7, kk = x&127
            WuB_s[x & 127][x >> 7] = Wu[(x >> 7) * 256 + 128 + (x & 127)];
        }
        __syncthreads();
        const int m = g >> 4, dc = g & 15;
        const int off   = (m == 0) ? 0   : (m == 1) ? 256 : 128;
        const int rbase = (m == 0) ? 128 : (m == 1) ? 256 : 384;
        const int k = t & 127, dh = t >> 7;
        const int d0 = dc * 8 + dh * 4;
        float a0 = 0, a1 = 0, a2 = 0, a3 = 0;
        for (int kk = 0; kk < 128; ++kk) {
            const float wu = WuB_s[kk][k];
            const float* wmp = Wm + kk * 384 + off + d0;
            a0 += wmp[0] * wu; a1 += wmp[1] * wu;
            a2 += wmp[2] * wu; a3 += wmp[3] * wu;
        }
        unsigned short* bp = BT + (size_t)k * 512 + rbase + d0;
        bp[0] = f2bf(a0); bp[1] = f2bf(a1); bp[2] = f2bf(a2); bp[3] = f2bf(a3);
    } else if (g == 48) {
        for (int p = 0; p < 64; ++p) {
            const int x = p * 256 + t, k = x >> 7, d = x & 127;
            BT[(size_t)k * 512 + d] = f2bf(Wu[k * 256 + d]);
        }
        if (t < 128) {
            float s = 0.f;
            for (int kk = 0; kk < 128; ++kk) s += bm[kk] * Wu[t * 256 + 128 + kk];
            bmWu[t] = s;
        }
    } else {                                        // g = 49..56: hbf cast
        const int bi = g - 49;
        const float4* h4 = (const float4*)h;
        uint2* hb2 = (uint2*)hbf;
        for (int p = 0; p < 32; ++p) {
            const int i4 = bi * 8192 + p * 256 + t;
            const float4 v = h4[i4];
            hb2[i4] = make_uint2((unsigned)f2bf(v.x) | ((unsigned)f2bf(v.y) << 16),
                                 (unsigned)f2bf(v.z) | ((unsigned)f2bf(v.w) << 16));
        }
    }
}

// es: es[b,j,d] = sum_i adj[b,i,j]*e[b,i,j,d] -> bf16.
// NEW vs R10: ballot-compacted nonzero-i list (pad to x32), then a
// BRANCH-FREE gather with 4 independent batched loads per iteration
// (n, n+8, n+16, n+24 — max index cntP-1, in bounds by construction).
// Full register budget (no min-waves clause) so loads stay in flight.
__global__ __launch_bounds__(256) void es_kernel(const float* __restrict__ e,
                                                 const float* __restrict__ adj,
                                                 unsigned short* __restrict__ esbf) {
    const int bj = blockIdx.x, t = threadIdx.x;
    const int b = bj >> 7, j = bj & 127;
    __shared__ float  sm_adj[NN];
    __shared__ int    sm_idx[NN];
    __shared__ float  sm_av[NN];
    __shared__ int    sm_cnt;
    __shared__ float4 red[8][32];
    if (t < NN) sm_adj[t] = adj[(size_t)(b * NN + t) * NN + j];
    __syncthreads();

    if (t < 64) {                                 // wave 0: ballot compaction
        const float a0 = sm_adj[t], a1 = sm_adj[t + 64];
        const unsigned long long m0 = __ballot(a0 != 0.0f);
        const unsigned long long m1 = __ballot(a1 != 0.0f);
        const int c0 = __popcll(m0);
        const unsigned long long below = (t == 0) ? 0ull : ((1ull << t) - 1ull);
        const int p0 = __popcll(m0 & below);
        const int p1 = c0 + __popcll(m1 & below);
        if (a0 != 0.0f) { sm_idx[p0] = t;      sm_av[p0] = a0; }
        if (a1 != 0.0f) { sm_idx[p1] = t + 64; sm_av[p1] = a1; }
        const int cnt = c0 + __popcll(m1);
        const int cntP = (cnt + 31) & ~31;        // pad to multiple of 32
        for (int x = cnt + t; x < cntP; x += 64) { sm_idx[x] = 0; sm_av[x] = 0.f; }
        if (t == 0) sm_cnt = cntP;
    }
    __syncthreads();
    const int cnt = sm_cnt;

    const int d4 = t & 31, g = t >> 5;            // 8 groups of 32 lanes
    const float4* __restrict__ ep =
        (const float4*)e + ((size_t)(b * NN) * NN + j) * 32 + d4;
    f4v acc = {0.f, 0.f, 0.f, 0.f};
    for (int base = 0; base < cnt; base += 32) {
        const int n = base + g;
        const int   iA = sm_idx[n];      const float aA = sm_av[n];
        const int   iB = sm_idx[n + 8];  const float aB = sm_av[n + 8];
        const int   iC = sm_idx[n + 16]; const float aC = sm_av[n + 16];
        const int   iD = sm_idx[n + 24]; const float aD = sm_av[n + 24];
        const float4 vA = ep[(size_t)iA * (NN * 32)];
        const float4 vB = ep[(size_t)iB * (NN * 32)];
        const float4 vC = ep[(size_t)iC * (NN * 32)];
        const float4 vD = ep[(size_t)iD * (NN * 32)];
        acc.x += aA * vA.x + aB * vB.x + aC * vC.x + aD * vD.x;
        acc.y += aA * vA.y + aB * vB.y + aC * vC.y + aD * vD.y;
        acc.z += aA * vA.z + aB * vB.z + aC * vC.z + aD * vD.z;
        acc.w += aA * vA.w + aB * vB.w + aC * vC.w + aD * vD.w;
    }
    red[g][d4] = make_float4(acc.x, acc.y, acc.z, acc.w);
    __syncthreads();
    if (t < 32) {
        float4 s = red[0][t];
        #pragma unroll
        for (int r = 1; r < 8; ++r) {
            const float4 v = red[r][t];
            s.x += v.x; s.y += v.y; s.z += v.z; s.w += v.w;
        }
        ((uint2*)esbf)[(size_t)bj * 32 + t] =
            make_uint2((unsigned)f2bf(s.x) | ((unsigned)f2bf(s.y) << 16),
                       (unsigned)f2bf(s.z) | ((unsigned)f2bf(s.w) << 16));
    }
}

// ah: AH[b,j,k] = sum_i adj[i,j]*h[b,i,k] (fp32) -> bf16; also deg[b,j].
__global__ __launch_bounds__(1024) void ah_kernel(
    const float* __restrict__ h, const float* __restrict__ adj,
    unsigned short* __restrict__ AHbf, float* __restrict__ deg) {
    const int blk = blockIdx.x;
    const int b = blk >> 4, jbase = (blk & 15) * 8;
    const int t = threadIdx.x;
    __shared__ float adj_s[8][NN];
    {
        const int i = t >> 3, j2 = t & 7;
        adj_s[j2][i] = adj[(size_t)(b * NN + i) * NN + jbase + j2];
    }
    __syncthreads();
    if (t < 256) {
        const int jj = t >> 5, l = t & 31;
        float s = adj_s[jj][l] + adj_s[jj][l + 32] + adj_s[jj][l + 64] + adj_s[jj][l + 96];
        #pragma unroll
        for (int off = 16; off; off >>= 1) s += __shfl_xor(s, off);
        if (l == 0) deg[b * NN + jbase + jj] = s;
    }
    const int k = t & 127, jl = t >> 7;
    float a0 = 0.f;
    const float* __restrict__ hp = h + (size_t)b * NN * DD + k;
    #pragma unroll 8
    for (int m = 0; m < 32; ++m) {
        const float4 aA = *(const float4*)&adj_s[jl][4 * m];
        const float h0 = hp[(size_t)(4 * m + 0) * DD];
        const float h1 = hp[(size_t)(4 * m + 1) * DD];
        const float h2 = hp[(size_t)(4 * m + 2) * DD];
        const float h3 = hp[(size_t)(4 * m + 3) * DD];
        a0 += aA.x * h0 + aA.y * h1 + aA.z * h2 + aA.w * h3;
    }
    AHbf[(size_t)(b * NN + jbase + jl) * DD + k] = f2bf(a0);
}

// out: MFMA GEMM. acc1 = [h|AH|es]·[WuAT;G1T;G3T]; acc2 = h·G2T.
// out = acc1 + deg*acc2 + deg*bmWu + bu.
__global__ __launch_bounds__(256) void out_kernel(
    const unsigned short* __restrict__ hbf, const unsigned short* __restrict__ AHbf,
    const unsigned short* __restrict__ esbf, const unsigned short* __restrict__ BT,
    const float* __restrict__ deg, const float* __restrict__ bmWu,
    const float* __restrict__ bu, float* __restrict__ out) {
    const int rt = blockIdx.x >> 2, ct = blockIdx.x & 3;
    const int t = threadIdx.x;
    const int l = t & 63, wid = t >> 6, mw = wid >> 1, nw = wid & 1;
    __shared__ unsigned short A_s[32][72], B_s[32][72], B2_s[32][72];
    f4v acc1 = {0.f, 0.f, 0.f, 0.f};
    f4v acc2 = {0.f, 0.f, 0.f, 0.f};
    const int rA = t >> 3, cb = t & 7;
    const int arow = mw * 16 + (l & 15);
    const int brow = nw * 16 + (l & 15);
    const int lg = l >> 4;
    for (int c = 0; c < 6; ++c) {
        __syncthreads();
        const unsigned short* src = (c < 2) ? hbf : (c < 4) ? AHbf : esbf;
        const int col0 = (c & 1) * 64;
        const int rowg = rt * 32 + rA;
        *(s8v*)&A_s[rA][cb * 8] = *(const s8v*)&src[(size_t)rowg * 128 + col0 + cb * 8];
        *(s8v*)&B_s[rA][cb * 8] =
            *(const s8v*)&BT[(size_t)(ct * 32 + rA) * 512 + c * 64 + cb * 8];
        if (c < 2)
            *(s8v*)&B2_s[rA][cb * 8] =
                *(const s8v*)&BT[(size_t)(ct * 32 + rA) * 512 + 384 + c * 64 + cb * 8];
        __syncthreads();
        #pragma unroll
        for (int kit = 0; kit < 2; ++kit) {
            const s8v a  = *(const s8v*)&A_s[arow][kit * 32 + lg * 8];
            const s8v bb = *(const s8v*)&B_s[brow][kit * 32 + lg * 8];
            acc1 = __builtin_amdgcn_mfma_f32_16x16x32_bf16(a, bb, acc1, 0, 0, 0);
            if (c < 2) {
                const s8v b2 = *(const s8v*)&B2_s[brow][kit * 32 + lg * 8];
                acc2 = __builtin_amdgcn_mfma_f32_16x16x32_bf16(a, b2, acc2, 0, 0, 0);
            }
        }
    }
    const int colk = ct * 32 + nw * 16 + (l & 15);
    const float bmv = bmWu[colk], buv = bu[colk];
    #pragma unroll
    for (int r = 0; r < 4; ++r) {
        const int rowg = rt * 32 + mw * 16 + (l >> 4) * 4 + r;
        const float dg = deg[rowg];
        out[(size_t)rowg * 128 + colk] = acc1[r] + dg * acc2[r] + dg * bmv + buv;
    }
}

extern "C" void kernel_launch(void* const* d_in, const int* in_sizes, int n_in,
                              void* d_out, int out_size, void* d_ws, size_t ws_size,
                              hipStream_t stream) {
    const float* h   = (const float*)d_in[0];
    const float* adj = (const float*)d_in[1];
    const float* e   = (const float*)d_in[2];
    const float* Wm  = (const float*)d_in[3];
    const float* bm  = (const float*)d_in[4];
    const float* Wu  = (const float*)d_in[5];
    const float* bu  = (const float*)d_in[6];
    float* out = (float*)d_out;

    float* ws = (float*)d_ws;
    unsigned short* BT   = (unsigned short*)ws;             // 128x512 bf16
    float*          bmWu = ws + 32768;                      // 128 f32
    float*          deg  = ws + 32896;                      // 2048 f32
    unsigned short* hbf  = (unsigned short*)(ws + 34944);   // 2048x128 bf16
    unsigned short* AHbf = (unsigned short*)(ws + 166016);  // 2048x128 bf16
    unsigned short* esbf = (unsigned short*)(ws + 297088);  // 2048x128 bf16

    prep_kernel<<<57, 256, 0, stream>>>(h, Wm, bm, Wu, BT, bmWu, hbf);
    es_kernel<<<BB * NN, 256, 0, stream>>>(e, adj, esbf);
    ah_kernel<<<BB * (NN / 8), 1024, 0, stream>>>(h, adj, AHbf, deg);
    out_kernel<<<256, 256, 0, stream>>>(hbf, AHbf, esbf, BT, deg, bmWu, bu, out);
}

// Round 17
// 34.369 us; speedup vs baseline: 2.5778x; 1.0889x over previous
//
#include <hip/hip_runtime.h>
#include <hip/hip_bf16.h>

#define BB 16
#define NN 128
#define DD 128

typedef __attribute__((ext_vector_type(8))) short s8v;   // 8 bf16 (4 VGPRs)
typedef __attribute__((ext_vector_type(4))) float f4v;   // MFMA C/D

__device__ __forceinline__ unsigned short f2bf(float f) {
    __hip_bfloat16 b = __float2bfloat16(f);
    return *reinterpret_cast<unsigned short*>(&b);
}

// front: ROLE-ORDERED fusion. Roles dispatch FIRST (low blockIdx) so the
// small prep/ah jobs run concurrently with the fabric-bound es stream
// (R15 had roles last -> they serialized after es -> neutral).
//   bid 0..47   : prep G-GEMM (chunked 16-KB staging, R15-proven)
//   bid 48      : WuA copy + bmWu
//   bid 49..56  : h -> bf16 cast
//   bid 57..312 : ah + deg (R15-proven 256-thread body)
//   bid 313..   : es (R16-proven compacted branch-free gather)
__global__ __launch_bounds__(256) void front_kernel(
    const float* __restrict__ h, const float* __restrict__ adj,
    const float* __restrict__ e, const float* __restrict__ Wm,
    const float* __restrict__ bm, const float* __restrict__ Wu,
    unsigned short* __restrict__ BT, float* __restrict__ bmWu,
    unsigned short* __restrict__ hbf, unsigned short* __restrict__ esbf,
    unsigned short* __restrict__ AHbf, float* __restrict__ deg) {
    const int bid = blockIdx.x, t = threadIdx.x;

    __shared__ float sm_big[4096];      // 16 KB: prep chunk / ah adj_s / es red
    __shared__ float sm_adj[NN];
    __shared__ int   sm_idx[NN];
    __shared__ float sm_av[NN];
    __shared__ int   sm_cnt;

    if (bid < 48) {
        // -------- prep: G_m[k][d] = sum_kk Wm[kk,off+d]*Wu[k,128+kk] --------
        float* chunk = sm_big;                        // [32][128] = 16 KB
        const int m = bid >> 4, dc = bid & 15;
        const int off   = (m == 0) ? 0   : (m == 1) ? 256 : 128;
        const int rbase = (m == 0) ? 128 : (m == 1) ? 256 : 384;
        const int k = t & 127, dh = t >> 7;
        const int d0 = dc * 8 + dh * 4;
        float a0 = 0, a1 = 0, a2 = 0, a3 = 0;
        for (int c = 0; c < 4; ++c) {
            for (int x = t; x < 32 * 128; x += 256) {
                const int kk = x >> 7, kcol = x & 127;
                chunk[kk * 128 + kcol] = Wu[kcol * 256 + 128 + c * 32 + kk];
            }
            __syncthreads();
            #pragma unroll 8
            for (int kk = 0; kk < 32; ++kk) {
                const float wu = chunk[kk * 128 + k];
                const float* wmp = Wm + (c * 32 + kk) * 384 + off + d0;
                a0 += wmp[0] * wu; a1 += wmp[1] * wu;
                a2 += wmp[2] * wu; a3 += wmp[3] * wu;
            }
            __syncthreads();
        }
        unsigned short* bp = BT + (size_t)k * 512 + rbase + d0;
        bp[0] = f2bf(a0); bp[1] = f2bf(a1); bp[2] = f2bf(a2); bp[3] = f2bf(a3);
    } else if (bid == 48) {
        for (int p = 0; p < 64; ++p) {                // WuA^T copy, BT rows 0-127
            const int x = p * 256 + t, k = x >> 7, d = x & 127;
            BT[(size_t)k * 512 + d] = f2bf(Wu[k * 256 + d]);
        }
        if (t < 128) {
            float s = 0.f;
            for (int kk = 0; kk < 128; ++kk) s += bm[kk] * Wu[t * 256 + 128 + kk];
            bmWu[t] = s;
        }
    } else if (bid < 57) {
        // -------- h -> bf16 cast --------
        const int bi = bid - 49;
        const float4* h4 = (const float4*)h;
        uint2* hb2 = (uint2*)hbf;
        for (int p = 0; p < 32; ++p) {
            const int i4 = bi * 8192 + p * 256 + t;
            const float4 v = h4[i4];
            hb2[i4] = make_uint2((unsigned)f2bf(v.x) | ((unsigned)f2bf(v.y) << 16),
                                 (unsigned)f2bf(v.z) | ((unsigned)f2bf(v.w) << 16));
        }
    } else if (bid < 313) {
        // -------- ah role: AH[b,j,k] = sum_i adj[i,j]*h[b,i,k]; deg --------
        const int b2 = bid - 57;
        const int b = b2 >> 4, jbase = (b2 & 15) * 8;
        float (*adj_s)[NN] = (float (*)[NN])sm_big;   // [8][128] = 4 KB
        for (int x = t; x < 8 * NN; x += 256) {
            const int i = x >> 3, j2 = x & 7;
            adj_s[j2][i] = adj[(size_t)(b * NN + i) * NN + jbase + j2];
        }
        __syncthreads();
        {   // deg for the 8 j's: 8 groups of 32 lanes
            const int jj = t >> 5, l = t & 31;
            float s = adj_s[jj][l] + adj_s[jj][l + 32] + adj_s[jj][l + 64] + adj_s[jj][l + 96];
            #pragma unroll
            for (int off = 16; off; off >>= 1) s += __shfl_xor(s, off);
            if (l == 0) deg[b * NN + jbase + jj] = s;
        }
        const int k = t & 127, jh = t >> 7;           // j = jh, jh+2, jh+4, jh+6
        float a0 = 0.f, a1 = 0.f, a2 = 0.f, a3 = 0.f;
        const float* __restrict__ hp = h + (size_t)b * NN * DD + k;
        #pragma unroll 8
        for (int m = 0; m < 32; ++m) {
            const float4 aA = *(const float4*)&adj_s[jh][4 * m];
            const float4 aB = *(const float4*)&adj_s[jh + 2][4 * m];
            const float4 aC = *(const float4*)&adj_s[jh + 4][4 * m];
            const float4 aD = *(const float4*)&adj_s[jh + 6][4 * m];
            const float h0 = hp[(size_t)(4 * m + 0) * DD];
            const float h1 = hp[(size_t)(4 * m + 1) * DD];
            const float h2 = hp[(size_t)(4 * m + 2) * DD];
            const float h3 = hp[(size_t)(4 * m + 3) * DD];
            a0 += aA.x * h0 + aA.y * h1 + aA.z * h2 + aA.w * h3;
            a1 += aB.x * h0 + aB.y * h1 + aB.z * h2 + aB.w * h3;
            a2 += aC.x * h0 + aC.y * h1 + aC.z * h2 + aC.w * h3;
            a3 += aD.x * h0 + aD.y * h1 + aD.z * h2 + aD.w * h3;
        }
        AHbf[(size_t)(b * NN + jbase + jh) * DD + k]     = f2bf(a0);
        AHbf[(size_t)(b * NN + jbase + jh + 2) * DD + k] = f2bf(a1);
        AHbf[(size_t)(b * NN + jbase + jh + 4) * DD + k] = f2bf(a2);
        AHbf[(size_t)(b * NN + jbase + jh + 6) * DD + k] = f2bf(a3);
    } else {
        // -------- es role: compacted branch-free gather (R16-proven) --------
        const int bj = bid - 313;
        const int b = bj >> 7, j = bj & 127;
        float4 (*red)[32] = (float4 (*)[32])sm_big;   // 4 KB of sm_big
        if (t < NN) sm_adj[t] = adj[(size_t)(b * NN + t) * NN + j];
        __syncthreads();
        if (t < 64) {                                 // wave 0: ballot compaction
            const float a0 = sm_adj[t], a1 = sm_adj[t + 64];
            const unsigned long long m0 = __ballot(a0 != 0.0f);
            const unsigned long long m1 = __ballot(a1 != 0.0f);
            const int c0 = __popcll(m0);
            const unsigned long long below = (t == 0) ? 0ull : ((1ull << t) - 1ull);
            const int p0 = __popcll(m0 & below);
            const int p1 = c0 + __popcll(m1 & below);
            if (a0 != 0.0f) { sm_idx[p0] = t;      sm_av[p0] = a0; }
            if (a1 != 0.0f) { sm_idx[p1] = t + 64; sm_av[p1] = a1; }
            const int cnt = c0 + __popcll(m1);
            const int cntP = (cnt + 31) & ~31;        // pad to multiple of 32
            for (int x = cnt + t; x < cntP; x += 64) { sm_idx[x] = 0; sm_av[x] = 0.f; }
            if (t == 0) sm_cnt = cntP;
        }
        __syncthreads();
        const int cnt = sm_cnt;
        const int d4 = t & 31, g = t >> 5;            // 8 groups of 32 lanes
        const float4* __restrict__ ep =
            (const float4*)e + ((size_t)(b * NN) * NN + j) * 32 + d4;
        f4v acc = {0.f, 0.f, 0.f, 0.f};
        for (int base = 0; base < cnt; base += 32) {
            const int n = base + g;
            const int   iA = sm_idx[n];      const float aA = sm_av[n];
            const int   iB = sm_idx[n + 8];  const float aB = sm_av[n + 8];
            const int   iC = sm_idx[n + 16]; const float aC = sm_av[n + 16];
            const int   iD = sm_idx[n + 24]; const float aD = sm_av[n + 24];
            const float4 vA = ep[(size_t)iA * (NN * 32)];
            const float4 vB = ep[(size_t)iB * (NN * 32)];
            const float4 vC = ep[(size_t)iC * (NN * 32)];
            const float4 vD = ep[(size_t)iD * (NN * 32)];
            acc.x += aA * vA.x + aB * vB.x + aC * vC.x + aD * vD.x;
            acc.y += aA * vA.y + aB * vB.y + aC * vC.y + aD * vD.y;
            acc.z += aA * vA.z + aB * vB.z + aC * vC.z + aD * vD.z;
            acc.w += aA * vA.w + aB * vB.w + aC * vC.w + aD * vD.w;
        }
        red[g][d4] = make_float4(acc.x, acc.y, acc.z, acc.w);
        __syncthreads();
        if (t < 32) {
            float4 s = red[0][t];
            #pragma unroll
            for (int r = 1; r < 8; ++r) {
                const float4 v = red[r][t];
                s.x += v.x; s.y += v.y; s.z += v.z; s.w += v.w;
            }
            ((uint2*)esbf)[(size_t)bj * 32 + t] =
                make_uint2((unsigned)f2bf(s.x) | ((unsigned)f2bf(s.y) << 16),
                           (unsigned)f2bf(s.z) | ((unsigned)f2bf(s.w) << 16));
        }
    }
}

// out: MFMA GEMM (R10-proven). acc1 = [h|AH|es]·[WuAT;G1T;G3T]; acc2 = h·G2T.
// out = acc1 + deg*acc2 + deg*bmWu + bu.
__global__ __launch_bounds__(256) void out_kernel(
    const unsigned short* __restrict__ hbf, const unsigned short* __restrict__ AHbf,
    const unsigned short* __restrict__ esbf, const unsigned short* __restrict__ BT,
    const float* __restrict__ deg, const float* __restrict__ bmWu,
    const float* __restrict__ bu, float* __restrict__ out) {
    const int rt = blockIdx.x >> 2, ct = blockIdx.x & 3;
    const int t = threadIdx.x;
    const int l = t & 63, wid = t >> 6, mw = wid >> 1, nw = wid & 1;
    __shared__ unsigned short A_s[32][72], B_s[32][72], B2_s[32][72];
    f4v acc1 = {0.f, 0.f, 0.f, 0.f};
    f4v acc2 = {0.f, 0.f, 0.f, 0.f};
    const int rA = t >> 3, cb = t & 7;
    const int arow = mw * 16 + (l & 15);
    const int brow = nw * 16 + (l & 15);
    const int lg = l >> 4;
    for (int c = 0; c < 6; ++c) {
        __syncthreads();
        const unsigned short* src = (c < 2) ? hbf : (c < 4) ? AHbf : esbf;
        const int col0 = (c & 1) * 64;
        const int rowg = rt * 32 + rA;
        *(s8v*)&A_s[rA][cb * 8] = *(const s8v*)&src[(size_t)rowg * 128 + col0 + cb * 8];
        *(s8v*)&B_s[rA][cb * 8] =
            *(const s8v*)&BT[(size_t)(ct * 32 + rA) * 512 + c * 64 + cb * 8];
        if (c < 2)
            *(s8v*)&B2_s[rA][cb * 8] =
                *(const s8v*)&BT[(size_t)(ct * 32 + rA) * 512 + 384 + c * 64 + cb * 8];
        __syncthreads();
        #pragma unroll
        for (int kit = 0; kit < 2; ++kit) {
            const s8v a  = *(const s8v*)&A_s[arow][kit * 32 + lg * 8];
            const s8v bb = *(const s8v*)&B_s[brow][kit * 32 + lg * 8];
            acc1 = __builtin_amdgcn_mfma_f32_16x16x32_bf16(a, bb, acc1, 0, 0, 0);
            if (c < 2) {
                const s8v b2 = *(const s8v*)&B2_s[brow][kit * 32 + lg * 8];
                acc2 = __builtin_amdgcn_mfma_f32_16x16x32_bf16(a, b2, acc2, 0, 0, 0);
            }
        }
    }
    const int colk = ct * 32 + nw * 16 + (l & 15);
    const float bmv = bmWu[colk], buv = bu[colk];
    #pragma unroll
    for (int r = 0; r < 4; ++r) {
        const int rowg = rt * 32 + mw * 16 + (l >> 4) * 4 + r;
        const float dg = deg[rowg];
        out[(size_t)rowg * 128 + colk] = acc1[r] + dg * acc2[r] + dg * bmv + buv;
    }
}

extern "C" void kernel_launch(void* const* d_in, const int* in_sizes, int n_in,
                              void* d_out, int out_size, void* d_ws, size_t ws_size,
                              hipStream_t stream) {
    const float* h   = (const float*)d_in[0];
    const float* adj = (const float*)d_in[1];
    const float* e   = (const float*)d_in[2];
    const float* Wm  = (const float*)d_in[3];
    const float* bm  = (const float*)d_in[4];
    const float* Wu  = (const float*)d_in[5];
    const float* bu  = (const float*)d_in[6];
    float* out = (float*)d_out;

    float* ws = (float*)d_ws;
    unsigned short* BT   = (unsigned short*)ws;             // 128x512 bf16
    float*          bmWu = ws + 32768;                      // 128 f32
    float*          deg  = ws + 32896;                      // 2048 f32
    unsigned short* hbf  = (unsigned short*)(ws + 34944);   // 2048x128 bf16
    unsigned short* AHbf = (unsigned short*)(ws + 166016);  // 2048x128 bf16
    unsigned short* esbf = (unsigned short*)(ws + 297088);  // 2048x128 bf16

    front_kernel<<<313 + BB * NN, 256, 0, stream>>>(h, adj, e, Wm, bm, Wu,
                                                    BT, bmWu, hbf, esbf, AHbf, deg);
    out_kernel<<<256, 256, 0, stream>>>(hbf, AHbf, esbf, BT, deg, bmWu, bu, out);
}